// Round 5
// baseline (87.146 us; speedup 1.0000x reference)
//
#include <hip/hip_runtime.h>

// Fully-fused 3x Minkowski sum-pool (3x3, stride 2, pad 1) with coordinate masks.
// feat (4,1024,1024,16) f32, mask (4,1024,1024) i32 -> out = concat(c2, c3).
// R5: quad-row sweep — 2 c1 rows (4 feat rows) per iteration. Doubles prefetch
// slack, halves barriers (36/block), uniform c2-row-per-iteration schedule.

constexpr int Hh = 1024, Ww = 1024;
constexpr int TW3 = 16, TH3 = 8;           // c3 tile per block
constexpr int NU = 4 * TW3 + 3;            // 67 c1 cols per block
constexpr int NV = 2 * TW3 + 1;            // 33 c2 cols per block
constexpr int NY = TW3;                    // 16 c3 cols
constexpr int NTH = 320;
constexpr int NQ = 2 * TH3 + 2;            // 18 quad iterations

// LDS-only barrier: wait own LDS ops, sync, leave global prefetch in flight.
#define BARRIER_LDS() asm volatile("s_waitcnt lgkmcnt(0)\ns_barrier" ::: "memory")

__device__ inline float4 add3(const float4& a, const float4& b, const float4& c) {
    return make_float4(a.x + b.x + c.x, a.y + b.y + c.y,
                       a.z + b.z + c.z, a.w + b.w + c.w);
}

__global__ __launch_bounds__(NTH) void fused3(
    const float* __restrict__ featp, const int* __restrict__ maskp,
    float4* __restrict__ c2o, float4* __restrict__ c3o)
{
    const int j = blockIdx.x;              // col strip (c3 cols [16j,16j+16))
    const int k = blockIdx.y;              // row chunk (c3 rows [8k,8k+8))
    const int b = blockIdx.z;
    const int P0 = TW3 * j, Q0 = TH3 * k;
    const int F0 = 8 * P0 - 7;             // feat col of u=0,dw=0
    const int T0 = 8 * Q0 - 6;             // first feat row of quad 0

    const int tid = threadIdx.x;
    const int c4 = tid & 3;                // which float4 of 16 channels
    const int u  = tid >> 2;               // col role index
    const bool aAct = tid < NU * 4;        // 268 threads: rs1/c1 role
    const bool vAct = tid < NV * 4;        // 132 threads: rs2/c2 role
    const bool yAct = tid < NY * 4;        //  64 threads: rs3/c3 role

    __shared__ float4 c1m[2][NU][5];       // [0]=c1 row s0, [1]=row s1 of the quad
    __shared__ float4 c2mS[NV][5];
    __shared__ unsigned char m1L[2][NU];
    __shared__ unsigned char m2L[NV];

    const float4* feat4 = reinterpret_cast<const float4*>(featp);
    const float4 z4 = make_float4(0.f, 0.f, 0.f, 0.f);

    auto ldMaskRow = [&](int t, int* mm) {
        mm[0] = mm[1] = mm[2] = 0;
        if (aAct && (unsigned)t < (unsigned)Hh) {
            const int base = (b * Hh + t) * Ww;
#pragma unroll
            for (int dw = 0; dw < 3; ++dw) {
                const int fc = F0 + 2 * u + dw;
                if ((unsigned)fc < (unsigned)Ww) mm[dw] = maskp[base + fc];
            }
        }
    };
    auto ldFeatRow = [&](int t, const int* mm, float4* ff) {
        ff[0] = ff[1] = ff[2] = z4;
        if (aAct && (unsigned)t < (unsigned)Hh) {
            const size_t base = (size_t)(b * Hh + t) * Ww;
#pragma unroll
            for (int dw = 0; dw < 3; ++dw) {
                if (mm[dw])   // masked-out pixels are never fetched
                    ff[dw] = feat4[(base + (F0 + 2 * u + dw)) * 4 + c4];
            }
        }
    };

    // ---- prologue ----
    int mBufA[12], mBufB[12];
    float4 ff[12];
    float4 h_prev;                         // rowsum of feat row (quad start - 1)
    int mp0, mp1;                          // m1 occupancy of the quad's 2 c1 rows
    {
        int mP[3];
        ldMaskRow(T0 - 1, mP);
        ldMaskRow(T0 + 0, mBufA + 0);
        ldMaskRow(T0 + 1, mBufA + 3);
        ldMaskRow(T0 + 2, mBufA + 6);
        ldMaskRow(T0 + 3, mBufA + 9);
        ldMaskRow(T0 + 4, mBufB + 0);      // quad-1 masks
        ldMaskRow(T0 + 5, mBufB + 3);
        ldMaskRow(T0 + 6, mBufB + 6);
        ldMaskRow(T0 + 7, mBufB + 9);
        float4 fP[3];
        ldFeatRow(T0 - 1, mP, fP);
        ldFeatRow(T0 + 0, mBufA + 0, ff + 0);
        ldFeatRow(T0 + 1, mBufA + 3, ff + 3);
        ldFeatRow(T0 + 2, mBufA + 6, ff + 6);
        ldFeatRow(T0 + 3, mBufA + 9, ff + 9);
        h_prev = add3(fP[0], fP[1], fP[2]);
        mp0 = mBufA[1] | mBufA[2] | mBufA[4]  | mBufA[5];
        mp1 = mBufA[7] | mBufA[8] | mBufA[10] | mBufA[11];
    }

    float4 r2p0 = z4, r2p1 = z4;           // rs2 of prev quad's 2 rows
    float4 r3p0 = z4, r3p1 = z4;           // rs3 of prev 2 quads
    int m2save = 0, m3save = 0;

    // mCur: masks gating quad i+1's feat (consumed now); mNxt: filled with quad i+2
    auto body = [&](int i, int (&mCur)[12], int (&mNxt)[12]) {
        // 1. consume feat quad i -> c1 rows s0 = S0+2i, s1 = s0+1  (S0 = 4Q0-3)
        const float4 hc0 = add3(ff[0], ff[1], ff[2]);
        const float4 hc1 = add3(ff[3], ff[4], ff[5]);
        const float4 hc2 = add3(ff[6], ff[7], ff[8]);
        const float4 hc3 = add3(ff[9], ff[10], ff[11]);
        if (aAct) {
            float4 cv0 = z4, cv1 = z4;
            if (mp0) cv0 = add3(h_prev, hc0, hc1);
            if (mp1) cv1 = add3(hc1, hc2, hc3);
            c1m[0][u][c4] = cv0;
            c1m[1][u][c4] = cv1;
            if (c4 == 0) {
                m1L[0][u] = (unsigned char)(mp0 ? 1 : 0);
                m1L[1][u] = (unsigned char)(mp1 ? 1 : 0);
            }
        }
        h_prev = hc3;
        // 2. next-quad occupancy pairs, then prefetch (feat i+1, masks i+2)
        mp0 = mCur[1] | mCur[2] | mCur[4]  | mCur[5];
        mp1 = mCur[7] | mCur[8] | mCur[10] | mCur[11];
        const int tq = T0 + 4 * (i + 1);
        if (i + 1 < NQ) {
            ldFeatRow(tq + 0, mCur + 0, ff + 0);
            ldFeatRow(tq + 1, mCur + 3, ff + 3);
            if (i + 1 != NQ - 1) {         // last quad only needs its first 2 rows
                ldFeatRow(tq + 2, mCur + 6, ff + 6);
                ldFeatRow(tq + 3, mCur + 9, ff + 9);
            }
        }
        if (i + 2 < NQ) {
            ldMaskRow(tq + 4, mNxt + 0);
            ldMaskRow(tq + 5, mNxt + 3);
            ldMaskRow(tq + 6, mNxt + 6);
            ldMaskRow(tq + 7, mNxt + 9);
        }
        // 3. c1 handoff -> rs2 (both rows, one barrier)
        BARRIER_LDS();
        float4 r2c0 = z4, r2c1 = z4;
        int m2p0 = 0, m2p1 = 0;
        if (vAct) {
            r2c0 = add3(c1m[0][2 * u + 0][c4], c1m[0][2 * u + 1][c4], c1m[0][2 * u + 2][c4]);
            r2c1 = add3(c1m[1][2 * u + 0][c4], c1m[1][2 * u + 1][c4], c1m[1][2 * u + 2][c4]);
            m2p0 = m1L[0][2 * u + 1] | m1L[0][2 * u + 2];
            m2p1 = m1L[1][2 * u + 1] | m1L[1][2 * u + 2];
        }
        // 4. c2 row r = 2Q0-2+i completes (i>=1)
        if (vAct && i >= 1) {
            const int m2 = m2save | m2p0;
            float4 c2v = z4;
            if (m2) c2v = add3(r2p0, r2p1, r2c0);
            if (i >= 2 && u >= 1) {        // owned rows r>=2Q0, owned cols
                const int r = 2 * Q0 - 2 + i;
                c2o[((size_t)((b * 256 + r) * 256 + (2 * P0 - 1 + u))) * 4 + c4] = c2v;
            }
            c2mS[u][c4] = c2v;
            if (c4 == 0) m2L[u] = (unsigned char)(m2 ? 1 : 0);
        }
        // 5. c2 handoff -> rs3
        BARRIER_LDS();
        float4 r3c = z4; int m3p = 0;
        if (yAct && i >= 1) {
            r3c = add3(c2mS[2 * u + 0][c4], c2mS[2 * u + 1][c4], c2mS[2 * u + 2][c4]);
            m3p = m2L[2 * u + 1] | m2L[2 * u + 2];
        }
        if ((i & 1) == 0) {
            m3save = m3p;                  // r even: save for next completion
        } else if (yAct && i >= 3) {       // r odd: c3 row q completes
            const int m3 = m3save | m3p;
            float4 c3v = z4;
            if (m3) c3v = add3(r3p0, r3p1, r3c);
            const int q = Q0 + ((i - 3) >> 1);
            c3o[((size_t)((b * 128 + q) * 128 + (P0 + u))) * 4 + c4] = c3v;
        }
        // 6. history shifts
        r3p0 = r3p1; r3p1 = r3c;
        r2p0 = r2c0; r2p1 = r2c1;
        m2save = m2p1;
    };

    for (int ii = 0; ii < NQ; ii += 2) {   // 2-unrolled: static mask-buffer roles
        body(ii + 0, mBufB, mBufA);
        body(ii + 1, mBufA, mBufB);
    }
}

extern "C" void kernel_launch(void* const* d_in, const int* in_sizes, int n_in,
                              void* d_out, int out_size, void* d_ws, size_t ws_size,
                              hipStream_t stream)
{
    const float* feat = (const float*)d_in[0];
    const int*   mask = (const int*)d_in[1];
    float4* c2 = (float4*)d_out;
    float4* c3 = c2 + (size_t)4 * 256 * 256 * 4;   // 4*256*256*16 floats ahead

    dim3 grid(Ww / (8 * TW3) /*8*/, Hh / (8 * TH3) /*16*/, 4);
    fused3<<<grid, NTH, 0, stream>>>(feat, mask, c2, c3);
}

// Round 6
// 83.582 us; speedup vs baseline: 1.0426x; 1.0426x over previous
//
#include <hip/hip_runtime.h>

// Fully-fused 3x Minkowski sum-pool (3x3, stride 2, pad 1) with coordinate masks.
// feat (4,1024,1024,16) f32, mask (4,1024,1024) i32 -> out = concat(c2, c3).
// R6 = R4 (pair-row sweep) with TH3 4: grid 1024 blocks (4/CU, 20 waves/CU).
// Single-axis occupancy experiment vs R4's 2 blocks/CU.

constexpr int Hh = 1024, Ww = 1024;
constexpr int TW3 = 16, TH3 = 4;           // c3 tile per block
constexpr int NU = 4 * TW3 + 3;            // 67 c1 cols per block
constexpr int NV = 2 * TW3 + 1;            // 33 c2 cols per block
constexpr int NY = TW3;                    // 16 c3 cols
constexpr int NTH = 320;
constexpr int NS = 4 * TH3 + 3;            // 19 c1 rows per block sweep

// LDS-only barrier: wait own LDS ops, sync, leave global prefetch in flight.
#define BARRIER_LDS() asm volatile("s_waitcnt lgkmcnt(0)\ns_barrier" ::: "memory")

__device__ inline float4 add3(const float4& a, const float4& b, const float4& c) {
    return make_float4(a.x + b.x + c.x, a.y + b.y + c.y,
                       a.z + b.z + c.z, a.w + b.w + c.w);
}

__global__ __launch_bounds__(NTH) void fused3(
    const float* __restrict__ featp, const int* __restrict__ maskp,
    float4* __restrict__ c2o, float4* __restrict__ c3o)
{
    const int j = blockIdx.x;              // col strip (c3 cols [16j,16j+16))
    const int k = blockIdx.y;              // row chunk (c3 rows [4k,4k+4))
    const int b = blockIdx.z;
    const int P0 = TW3 * j, Q0 = TH3 * k;
    const int F0 = 8 * P0 - 7;             // feat col of u=0,dw=0
    const int S0 = 4 * Q0 - 3;             // first c1 row of sweep

    const int tid = threadIdx.x;
    const int c4 = tid & 3;                // which float4 of 16 channels
    const int u  = tid >> 2;               // col role index
    const bool aAct = tid < NU * 4;        // 268 threads: rs1/c1 role
    const bool vAct = tid < NV * 4;        // 132 threads: rs2/c2 role
    const bool yAct = tid < NY * 4;        //  64 threads: rs3/c3 role

    __shared__ float4 c1m[2][NU][5];       // double-buffered handoff
    __shared__ float4 c2mS[NV][5];         // single buffer (2 barriers apart)
    __shared__ unsigned char m1L[2][NU];
    __shared__ unsigned char m2L[NV];

    const float4* feat4 = reinterpret_cast<const float4*>(featp);
    const float4 z4 = make_float4(0.f, 0.f, 0.f, 0.f);

    auto ldMaskRow = [&](int t, int* mm) {
        mm[0] = mm[1] = mm[2] = 0;
        if (aAct && (unsigned)t < (unsigned)Hh) {
            const int base = (b * Hh + t) * Ww;
#pragma unroll
            for (int dw = 0; dw < 3; ++dw) {
                const int fc = F0 + 2 * u + dw;
                if ((unsigned)fc < (unsigned)Ww) mm[dw] = maskp[base + fc];
            }
        }
    };
    auto ldFeatRow = [&](int t, const int* mm, float4* ff) {
        ff[0] = ff[1] = ff[2] = z4;
        if (aAct && (unsigned)t < (unsigned)Hh) {
            const size_t base = (size_t)(b * Hh + t) * Ww;
#pragma unroll
            for (int dw = 0; dw < 3; ++dw) {
                if (mm[dw])   // masked-out pixels are never fetched
                    ff[dw] = feat4[(base + (F0 + 2 * u + dw)) * 4 + c4];
            }
        }
    };

    // ---- prologue: pair 0 resident, pair-1 masks resident, prev-row sum ----
    int   mA[6];        // masks of pair i+1 (entering iter i)
    float4 ffA[6];      // feat of pair i (masked)
    float4 h_prev;      // rowsum of feat row 2s-1
    int   mp_cur;       // m1 occupancy OR for pair i
    {
        int mP[3], m0[6];
        ldMaskRow(2 * S0 - 1, mP);
        ldMaskRow(2 * S0,     m0);
        ldMaskRow(2 * S0 + 1, m0 + 3);
        ldMaskRow(2 * S0 + 2, mA);
        ldMaskRow(2 * S0 + 3, mA + 3);
        float4 fP[3];
        ldFeatRow(2 * S0 - 1, mP, fP);
        ldFeatRow(2 * S0,     m0, ffA);
        ldFeatRow(2 * S0 + 1, m0 + 3, ffA + 3);
        h_prev = add3(fP[0], fP[1], fP[2]);
        mp_cur = m0[1] | m0[2] | m0[4] | m0[5];
    }

    float4 r2h0 = z4, r2h1 = z4;           // rs2 history (s-2, s-1)
    float4 r3h0 = z4, r3h1 = z4;           // rs3 history (r-2, r-1)
    int m2save = 0, m3save = 0;

    for (int i = 0; i < NS; ++i) {
        const int sb = i & 1;
        // 1. consume feat pair i -> c1 row s = S0+i
        const float4 hc_e = add3(ffA[0], ffA[1], ffA[2]);
        const float4 hc_o = add3(ffA[3], ffA[4], ffA[5]);
        if (aAct) {
            float4 cv = z4;
            if (mp_cur) cv = add3(h_prev, hc_e, hc_o);
            c1m[sb][u][c4] = cv;
            if (c4 == 0) m1L[sb][u] = (unsigned char)(mp_cur ? 1 : 0);
        }
        // 2. prefetch: feat pair i+1 (gated by mA), masks pair i+2
        const float4 hp_new = hc_o;
        const int mp_new = mA[1] | mA[2] | mA[4] | mA[5];
        const int t2 = 2 * (S0 + i) + 2;
        if (i + 1 < NS) {
            ldFeatRow(t2,     mA,     ffA);
            ldFeatRow(t2 + 1, mA + 3, ffA + 3);
        }
        if (i + 2 < NS) {
            ldMaskRow(t2 + 2, mA);
            ldMaskRow(t2 + 3, mA + 3);
        }
        // 3. c1 handoff -> rs2
        BARRIER_LDS();
        float4 r2c = z4; int m2p = 0;
        if (vAct) {
            const float4 a0 = c1m[sb][2 * u + 0][c4];
            const float4 a1 = c1m[sb][2 * u + 1][c4];
            const float4 a2 = c1m[sb][2 * u + 2][c4];
            r2c = add3(a0, a1, a2);
            m2p = m1L[sb][2 * u + 1] | m1L[sb][2 * u + 2];
        }
        if ((i & 1) == 0) {
            // c2 row r = 2*Q0 - 2 + i/2 completes
            const int r = 2 * Q0 - 2 + (i >> 1);
            if (vAct) {
                const int m2 = m2save | m2p;
                float4 c2v = z4;
                if (m2) c2v = add3(r2h0, r2h1, r2c);
                if (i >= 4 && u >= 1)   // owned rows r>=2Q0, owned cols
                    c2o[((size_t)((b * 256 + r) * 256 + (2 * P0 - 1 + u))) * 4 + c4] = c2v;
                c2mS[u][c4] = c2v;
                if (c4 == 0) m2L[u] = (unsigned char)(m2 ? 1 : 0);
            }
            BARRIER_LDS();
            float4 r3c = z4; int m3p = 0;
            if (yAct) {
                const float4 b0 = c2mS[2 * u + 0][c4];
                const float4 b1 = c2mS[2 * u + 1][c4];
                const float4 b2 = c2mS[2 * u + 2][c4];
                r3c = add3(b0, b1, b2);
                m3p = m2L[2 * u + 1] | m2L[2 * u + 2];
            }
            if ((i & 2) == 0) {          // r even: save
                m3save = m3p;
            } else if (yAct && i >= 6) { // r odd: c3 row q completes
                const int m3 = m3save | m3p;
                float4 c3v = z4;
                if (m3) c3v = add3(r3h0, r3h1, r3c);
                const int q = Q0 + ((i - 6) >> 2);
                c3o[((size_t)((b * 128 + q) * 128 + (P0 + u))) * 4 + c4] = c3v;
            }
            r3h0 = r3h1; r3h1 = r3c;
        } else {
            m2save = m2p;                // s = 2r: save for next completion
        }
        r2h0 = r2h1; r2h1 = r2c;
        h_prev = hp_new; mp_cur = mp_new;
    }
}

extern "C" void kernel_launch(void* const* d_in, const int* in_sizes, int n_in,
                              void* d_out, int out_size, void* d_ws, size_t ws_size,
                              hipStream_t stream)
{
    const float* feat = (const float*)d_in[0];
    const int*   mask = (const int*)d_in[1];
    float4* c2 = (float4*)d_out;
    float4* c3 = c2 + (size_t)4 * 256 * 256 * 4;   // 4*256*256*16 floats ahead

    dim3 grid(Ww / (8 * TW3) /*8*/, Hh / (8 * TH3) /*32*/, 4);
    fused3<<<grid, NTH, 0, stream>>>(feat, mask, c2, c3);
}

// Round 7
// 60.475 us; speedup vs baseline: 1.4410x; 1.3821x over previous
//
#include <hip/hip_runtime.h>

// Fully-fused 3x Minkowski sum-pool (3x3, stride 2, pad 1) with coordinate masks.
// feat (4,1024,1024,16) f32, mask (4,1024,1024) i32 -> out = concat(c2, c3).
// R7 = R4 (pair-row sweep, 512 blocks) with ONE barrier per iteration:
// c2mS is written post-barrier at even i and read post-barrier at i+1 — the
// intervening barrier (lgkmcnt-drained) makes the single buffer race-free.
// Barriers 53 -> 36 per block; r2/r3 LDS phases decoupled across iterations.

constexpr int Hh = 1024, Ww = 1024;
constexpr int TW3 = 16, TH3 = 8;           // c3 tile per block
constexpr int NU = 4 * TW3 + 3;            // 67 c1 cols per block
constexpr int NV = 2 * TW3 + 1;            // 33 c2 cols per block
constexpr int NY = TW3;                    // 16 c3 cols
constexpr int NTH = 320;
constexpr int NS = 4 * TH3 + 3;            // 35 c1 rows per block sweep

// LDS-only barrier: wait own LDS ops, sync, leave global prefetch in flight.
#define BARRIER_LDS() asm volatile("s_waitcnt lgkmcnt(0)\ns_barrier" ::: "memory")

__device__ inline float4 add3(const float4& a, const float4& b, const float4& c) {
    return make_float4(a.x + b.x + c.x, a.y + b.y + c.y,
                       a.z + b.z + c.z, a.w + b.w + c.w);
}

__global__ __launch_bounds__(NTH) void fused3(
    const float* __restrict__ featp, const int* __restrict__ maskp,
    float4* __restrict__ c2o, float4* __restrict__ c3o)
{
    const int j = blockIdx.x;              // col strip (c3 cols [16j,16j+16))
    const int k = blockIdx.y;              // row chunk (c3 rows [8k,8k+8))
    const int b = blockIdx.z;
    const int P0 = TW3 * j, Q0 = TH3 * k;
    const int F0 = 8 * P0 - 7;             // feat col of u=0,dw=0
    const int S0 = 4 * Q0 - 3;             // first c1 row of sweep

    const int tid = threadIdx.x;
    const int c4 = tid & 3;                // which float4 of 16 channels
    const int u  = tid >> 2;               // col role index
    const bool aAct = tid < NU * 4;        // 268 threads: rs1/c1 role
    const bool vAct = tid < NV * 4;        // 132 threads: rs2/c2 role
    const bool yAct = tid < NY * 4;        //  64 threads: rs3/c3 role

    __shared__ float4 c1m[2][NU][5];       // double-buffered (write pre-bar, read post-bar)
    __shared__ float4 c2mS[NV][5];         // written post-bar(i), read post-bar(i+1)
    __shared__ unsigned char m1L[2][NU];
    __shared__ unsigned char m2L[NV];

    const float4* feat4 = reinterpret_cast<const float4*>(featp);
    const float4 z4 = make_float4(0.f, 0.f, 0.f, 0.f);

    auto ldMaskRow = [&](int t, int* mm) {
        mm[0] = mm[1] = mm[2] = 0;
        if (aAct && (unsigned)t < (unsigned)Hh) {
            const int base = (b * Hh + t) * Ww;
#pragma unroll
            for (int dw = 0; dw < 3; ++dw) {
                const int fc = F0 + 2 * u + dw;
                if ((unsigned)fc < (unsigned)Ww) mm[dw] = maskp[base + fc];
            }
        }
    };
    auto ldFeatRow = [&](int t, const int* mm, float4* ff) {
        ff[0] = ff[1] = ff[2] = z4;
        if (aAct && (unsigned)t < (unsigned)Hh) {
            const size_t base = (size_t)(b * Hh + t) * Ww;
#pragma unroll
            for (int dw = 0; dw < 3; ++dw) {
                if (mm[dw])   // masked-out pixels are never fetched
                    ff[dw] = feat4[(base + (F0 + 2 * u + dw)) * 4 + c4];
            }
        }
    };

    // ---- prologue: pair 0 resident, pair-1 masks resident, prev-row sum ----
    int   mA[6];        // masks of pair i+1 (entering iter i)
    float4 ffA[6];      // feat of pair i (masked)
    float4 h_prev;      // rowsum of feat row 2s-1
    int   mp_cur;       // m1 occupancy OR for pair i
    {
        int mP[3], m0[6];
        ldMaskRow(2 * S0 - 1, mP);
        ldMaskRow(2 * S0,     m0);
        ldMaskRow(2 * S0 + 1, m0 + 3);
        ldMaskRow(2 * S0 + 2, mA);
        ldMaskRow(2 * S0 + 3, mA + 3);
        float4 fP[3];
        ldFeatRow(2 * S0 - 1, mP, fP);
        ldFeatRow(2 * S0,     m0, ffA);
        ldFeatRow(2 * S0 + 1, m0 + 3, ffA + 3);
        h_prev = add3(fP[0], fP[1], fP[2]);
        mp_cur = m0[1] | m0[2] | m0[4] | m0[5];
    }

    float4 r2h0 = z4, r2h1 = z4;           // rs2 history (s-2, s-1)
    float4 r3h0 = z4, r3h1 = z4;           // rs3 history
    int m2save = 0, m3save = 0;

    for (int i = 0; i < NS; ++i) {
        const int sb = i & 1;
        // A: consume feat pair i -> c1 row s = S0+i (LDS write pre-barrier)
        const float4 hc_e = add3(ffA[0], ffA[1], ffA[2]);
        const float4 hc_o = add3(ffA[3], ffA[4], ffA[5]);
        if (aAct) {
            float4 cv = z4;
            if (mp_cur) cv = add3(h_prev, hc_e, hc_o);
            c1m[sb][u][c4] = cv;
            if (c4 == 0) m1L[sb][u] = (unsigned char)(mp_cur ? 1 : 0);
        }
        const float4 hp_new = hc_o;
        const int mp_new = mA[1] | mA[2] | mA[4] | mA[5];
        // B: prefetch issue — feat pair i+1 (gated by mA), masks pair i+2
        const int t2 = 2 * (S0 + i) + 2;
        if (i + 1 < NS) {
            ldFeatRow(t2,     mA,     ffA);
            ldFeatRow(t2 + 1, mA + 3, ffA + 3);
        }
        if (i + 2 < NS) {
            ldMaskRow(t2 + 2, mA);
            ldMaskRow(t2 + 3, mA + 3);
        }
        BARRIER_LDS();                     // the iteration's single barrier
        // C: r2 phase (post-barrier)
        float4 r2c = z4; int m2p = 0;
        if (vAct) {
            r2c = add3(c1m[sb][2 * u + 0][c4], c1m[sb][2 * u + 1][c4],
                       c1m[sb][2 * u + 2][c4]);
            m2p = m1L[sb][2 * u + 1] | m1L[sb][2 * u + 2];
        }
        if ((i & 1) == 0) {
            // c2 row r = 2*Q0 - 2 + i/2 completes; c2mS consumed at i+1
            if (vAct) {
                const int m2 = m2save | m2p;
                float4 c2v = z4;
                if (m2) c2v = add3(r2h0, r2h1, r2c);
                if (i >= 4 && u >= 1) {    // owned rows r>=2Q0, owned cols
                    const int r = 2 * Q0 - 2 + (i >> 1);
                    c2o[((size_t)((b * 256 + r) * 256 + (2 * P0 - 1 + u))) * 4 + c4] = c2v;
                }
                c2mS[u][c4] = c2v;
                if (c4 == 0) m2L[u] = (unsigned char)(m2 ? 1 : 0);
            }
        } else {
            m2save = m2p;
            // D: r3 phase — reads c2 row written post-barrier at i-1
            float4 r3c = z4; int m3p = 0;
            if (yAct) {
                r3c = add3(c2mS[2 * u + 0][c4], c2mS[2 * u + 1][c4],
                           c2mS[2 * u + 2][c4]);
                m3p = m2L[2 * u + 1] | m2L[2 * u + 2];
            }
            if (((i - 1) & 2) == 0) {      // c2 row even: save
                m3save = m3p;
            } else if (yAct && i >= 7) {   // c2 row odd: c3 row q completes
                const int m3 = m3save | m3p;
                float4 c3v = z4;
                if (m3) c3v = add3(r3h0, r3h1, r3c);
                const int q = Q0 + ((i - 7) >> 2);
                c3o[((size_t)((b * 128 + q) * 128 + (P0 + u))) * 4 + c4] = c3v;
            }
            r3h0 = r3h1; r3h1 = r3c;
        }
        r2h0 = r2h1; r2h1 = r2c;
        h_prev = hp_new; mp_cur = mp_new;
    }
    // epilogue: final r3/c3 (i_eff = NS = 35) reading c2mS written at i = 34
    BARRIER_LDS();
    if (yAct) {
        const float4 r3c = add3(c2mS[2 * u + 0][c4], c2mS[2 * u + 1][c4],
                                c2mS[2 * u + 2][c4]);
        const int m3p = m2L[2 * u + 1] | m2L[2 * u + 2];
        const int m3 = m3save | m3p;
        float4 c3v = z4;
        if (m3) c3v = add3(r3h0, r3h1, r3c);
        const int q = Q0 + ((NS - 7) >> 2);            // Q0 + 7
        c3o[((size_t)((b * 128 + q) * 128 + (P0 + u))) * 4 + c4] = c3v;
    }
}

extern "C" void kernel_launch(void* const* d_in, const int* in_sizes, int n_in,
                              void* d_out, int out_size, void* d_ws, size_t ws_size,
                              hipStream_t stream)
{
    const float* feat = (const float*)d_in[0];
    const int*   mask = (const int*)d_in[1];
    float4* c2 = (float4*)d_out;
    float4* c3 = c2 + (size_t)4 * 256 * 256 * 4;   // 4*256*256*16 floats ahead

    dim3 grid(Ww / (8 * TW3) /*8*/, Hh / (8 * TH3) /*16*/, 4);
    fused3<<<grid, NTH, 0, stream>>>(feat, mask, c2, c3);
}